// Round 7
// baseline (1778.497 us; speedup 1.0000x reference)
//
#include <hip/hip_runtime.h>
#include <hip/hip_bf16.h>
#include <cstdint>

// Neural ODE: 10 Heun steps of f(y) = tanh(y@W1 + b1)@W2 + b2
// BATCH=8192, D=512, H=2048, dt=0.1
// R7: CW 256->512 (NCH=4); each wave does 2 nb1 tiles (phase1) and 2 nb2
// tiles (phase2) SHARING the A-frag LDS reads -> per-CU ds_read_b128 count
// drops 6144->4096 per f-eval (was the top measured cost, ~31 us of LDS
// issue vs ~29 us L2 weight stream). Single 32 KB h buffer, sequential
// phases, 2 barriers/chunk (8 total, same as R6), static LDS stays 64 KB.

#define BATCHN 8192
#define DDIM 512
#define HDIM 2048
#define CW 512          // chunk width over H
#define NCH (HDIM / CW) // 4

typedef short short8 __attribute__((ext_vector_type(8)));
typedef float floatx4 __attribute__((ext_vector_type(4)));

__device__ __forceinline__ unsigned short f2bf(float f) {
  union { __hip_bfloat16 h; unsigned short u; } cv;
  cv.h = __float2bfloat16(f);
  return cv.u;
}

__device__ __forceinline__ float fast_tanh(float x) {
  float e = __expf(2.0f * x);
  return 1.0f - 2.0f / (e + 1.0f);
}

__device__ __forceinline__ void glds16(const void* g, void* l) {
  __builtin_amdgcn_global_load_lds(
      (const __attribute__((address_space(1))) void*)(uintptr_t)g,
      (__attribute__((address_space(3))) void*)(uint32_t)(uintptr_t)l,
      16, 0, 0);
}

// Fragment conventions (verified by R1-R6 passing kernels):
//  A-frag (16x16x32): lane holds A[m = l15][k = quad*8 + j], j=0..7 (16B)
//  B-frag:            lane holds B[n = l15][k = quad*8 + j]
//  C/D:               row = quad*4 + r, col = l15
// Packed buffers: frag f stored at [(f*64 + lane)*8] halves.
//  yPack: f = rb*16 + ks   (rb = batch-row/16: 0..511, ks = D k-step: 0..15)
//  w1p:   f = nb*16 + kb   (nb = H col-tile: 0..127,   kb = D k-step: 0..15)
//  w2p:   f = nb*64 + kb   (nb = D col-tile: 0..31,    kb = H k-step: 0..63)

__global__ __launch_bounds__(1024, 4) void fused_feval(
    const unsigned short* __restrict__ yPack,   // packed bf16 eval input
    const unsigned short* __restrict__ w1p,
    const unsigned short* __restrict__ w2p,
    const float* __restrict__ b1,
    const float* __restrict__ b2,
    const float* __restrict__ stateIn,   // EPI1: y fp32 ; EPI2: p fp32
    float* __restrict__ stateOut,        // EPI1: p      ; EPI2: ynew
    unsigned short* __restrict__ outPack,// packed bf16 next-eval input
    int epi) {                           // 1 or 2
  __shared__ unsigned short yA[32 * 512];   // 32 KB, frags (mt*16 + ks)
  __shared__ unsigned short hA[32 * CW];    // 32 KB, frags (mt*16 + ksa)

  const int tid  = threadIdx.x;
  const int lane = tid & 63;
  const int w    = tid >> 6;    // wave 0..15
  const int quad = lane >> 4;
  const int l15  = lane & 15;
  const int blk  = blockIdx.x;  // 0..255
  const int B0   = blk * 32;    // slab base row

  // phase0: linear copy of this block's 32 KB packed y-slab into LDS.
  {
    const unsigned short* src = yPack + (size_t)blk * (32 * 512);
    glds16(src + (size_t)tid * 8, &yA[tid * 8]);
    glds16(src + (size_t)(1024 + tid) * 8, &yA[(1024 + tid) * 8]);
  }
  __syncthreads();

  floatx4 accY[2][2] = {};  // ymid acc: (mt, i), cols (w*2+i)*16 + l15

  for (int c = 0; c < NCH; ++c) {
    // ---- phase1: h[:, c*CW ..] = tanh(y @ W1-slice + b1), 2 tiles/wave ----
    floatx4 acc1[2][2] = {};  // (t, mt)
#pragma unroll
    for (int ks = 0; ks < 16; ++ks) {
      short8 a0 = *(const short8*)&yA[((0 * 16 + ks) * 64 + lane) * 8];
      short8 a1 = *(const short8*)&yA[((1 * 16 + ks) * 64 + lane) * 8];
#pragma unroll
      for (int t = 0; t < 2; ++t) {
        const int nb1 = c * 32 + w * 2 + t;  // H col-tile 0..127
        short8 b = *(const short8*)&w1p[((size_t)(nb1 * 16 + ks) * 64 + lane) * 8];
        acc1[t][0] = __builtin_amdgcn_mfma_f32_16x16x32_bf16(a0, b, acc1[t][0], 0, 0, 0);
        acc1[t][1] = __builtin_amdgcn_mfma_f32_16x16x32_bf16(a1, b, acc1[t][1], 0, 0, 0);
      }
    }
    // bias + tanh + scatter into hA in A-frag layout (k = chunk-local h-col)
#pragma unroll
    for (int t = 0; t < 2; ++t) {
      const int kloc = (w * 2 + t) * 16 + l15;   // 0..511
      const float bb = b1[c * CW + kloc];
      const int ksa = kloc >> 5;
      const int qa  = (kloc & 31) >> 3;
      const int kb7 = kloc & 7;
#pragma unroll
      for (int mt = 0; mt < 2; ++mt)
#pragma unroll
        for (int r = 0; r < 4; ++r) {
          const int m15 = quad * 4 + r;          // C row -> A-frag m
          hA[((mt * 16 + ksa) * 64 + qa * 16 + m15) * 8 + kb7] =
              f2bf(fast_tanh(acc1[t][mt][r] + bb));
        }
    }
    __syncthreads();
    // ---- phase2: accY += h_chunk @ W2-slice (2 nb2 tiles share A-reads) ----
#pragma unroll
    for (int kb = 0; kb < 16; ++kb) {
      short8 a0 = *(const short8*)&hA[((0 * 16 + kb) * 64 + lane) * 8];
      short8 a1 = *(const short8*)&hA[((1 * 16 + kb) * 64 + lane) * 8];
      const int kbg = c * 16 + kb;               // global H k-step 0..63
#pragma unroll
      for (int i = 0; i < 2; ++i) {
        const int nb2 = w * 2 + i;               // D col-tile 0..31
        short8 b = *(const short8*)&w2p[((size_t)(nb2 * 64 + kbg) * 64 + lane) * 8];
        accY[0][i] = __builtin_amdgcn_mfma_f32_16x16x32_bf16(a0, b, accY[0][i], 0, 0, 0);
        accY[1][i] = __builtin_amdgcn_mfma_f32_16x16x32_bf16(a1, b, accY[1][i], 0, 0, 0);
      }
    }
    __syncthreads();  // protect hA before next chunk's phase1 overwrites it
  }

  // Epilogue: add b2, Heun combine with fp32 state, pack bf16 result.
  {
    unsigned short* pbuf = &hA[0];  // 32 KB staging, frags (mt*16 + ksa) over D
#pragma unroll
    for (int i = 0; i < 2; ++i) {
      const int ncol = (w * 2 + i) * 16 + l15;   // 0..511
      const float bb = b2[ncol];
      const int ksa = ncol >> 5;
      const int qa  = (ncol & 31) >> 3;
      const int nb7 = ncol & 7;
#pragma unroll
      for (int mt = 0; mt < 2; ++mt)
#pragma unroll
        for (int r = 0; r < 4; ++r) {
          const int row = B0 + mt * 16 + quad * 4 + r;
          const size_t idx = (size_t)row * DDIM + ncol;
          const float v = accY[mt][i][r] + bb;
          float nv;
          if (epi == 1) {
            const float y = stateIn[idx];
            stateOut[idx] = y + 0.05f * v;   // p = y + (dt/2)*k1
            nv = y + 0.1f * v;               // ymid
          } else {
            const float yn = stateIn[idx] + 0.05f * v;  // ynew = p + (dt/2)*k2
            stateOut[idx] = yn;
            nv = yn;
          }
          const int m15 = quad * 4 + r;
          pbuf[((mt * 16 + ksa) * 64 + qa * 16 + m15) * 8 + nb7] = f2bf(nv);
        }
    }
    __syncthreads();
    unsigned short* dst = outPack + (size_t)blk * (32 * 512);
#pragma unroll
    for (int p = 0; p < 2; ++p) {
      short8 v = *(const short8*)&pbuf[(size_t)(p * 1024 + tid) * 8];
      *(short8*)&dst[(size_t)(p * 1024 + tid) * 8] = v;
    }
  }
}

// Pack weight [K][N] fp32 -> B-frag order: frag f = nb*KB + kb,
// lane entry = src[kb*32 + quad*8 + j][nb*16 + l15].
__global__ void pack_b(const float* __restrict__ src, unsigned short* __restrict__ dst,
                       int KB, int N) {
  const int t = blockIdx.x * 256 + threadIdx.x;
  const int lane = t & 63, f = t >> 6;
  const int nb = f / KB, kb = f % KB;
  const int quad = lane >> 4, l15 = lane & 15;
  const int k0 = kb * 32 + quad * 8, n = nb * 16 + l15;
  short8 v;
#pragma unroll
  for (int j = 0; j < 8; ++j)
    v[j] = (short)f2bf(src[(size_t)(k0 + j) * N + n]);
  *(short8*)&dst[(size_t)t * 8] = v;
}

// y0 fp32 [8192][512] -> yF fp32 copy + packed bf16 A-frags.
__global__ void pack_y(const float* __restrict__ y0, float* __restrict__ yF,
                       unsigned short* __restrict__ ypk) {
  const int t = blockIdx.x * 256 + threadIdx.x;
  const int lane = t & 63, f = t >> 6;
  const int rb = f >> 4, ks = f & 15;
  const int quad = lane >> 4, l15 = lane & 15;
  const int row = rb * 16 + l15, c0 = ks * 32 + quad * 8;
  short8 v;
#pragma unroll
  for (int j = 0; j < 8; ++j) {
    const float x = y0[(size_t)row * DDIM + c0 + j];
    yF[(size_t)row * DDIM + c0 + j] = x;
    v[j] = (short)f2bf(x);
  }
  *(short8*)&ypk[(size_t)t * 8] = v;
}

extern "C" void kernel_launch(void* const* d_in, const int* in_sizes, int n_in,
                              void* d_out, int out_size, void* d_ws, size_t ws_size,
                              hipStream_t stream) {
  const float* y0 = (const float*)d_in[0];
  const float* W1 = (const float*)d_in[1];  // [512][2048]
  const float* b1 = (const float*)d_in[2];  // [2048]
  const float* W2 = (const float*)d_in[3];  // [2048][512]
  const float* b2 = (const float*)d_in[4];  // [512]

  char* ws = (char*)d_ws;
  float*          yF   = (float*)(ws);                         // 16 MB
  float*          pF   = (float*)(ws + (size_t)(16u << 20));   // 16 MB
  unsigned short* ypk  = (unsigned short*)(ws + (size_t)(32u << 20)); // 8 MB
  unsigned short* ympk = (unsigned short*)(ws + (size_t)(40u << 20)); // 8 MB
  unsigned short* w1p  = (unsigned short*)(ws + (size_t)(48u << 20)); // 2 MB
  unsigned short* w2p  = (unsigned short*)(ws + (size_t)(50u << 20)); // 2 MB

  // Pre-pass: pack weights (2048 frags each) and y0 (8192 frags).
  pack_b<<<512, 256, 0, stream>>>(W1, w1p, 16, HDIM);
  pack_b<<<512, 256, 0, stream>>>(W2, w2p, 64, DDIM);
  pack_y<<<2048, 256, 0, stream>>>(y0, yF, ypk);

  const dim3 grid(256), blkd(1024);
  for (int s = 0; s < 10; ++s) {
    // eval1: k1 = f(y); p = y + 0.05*k1; ymid = y + 0.1*k1 (packed)
    fused_feval<<<grid, blkd, 0, stream>>>(ypk, w1p, w2p, b1, b2, yF, pF, ympk, 1);
    // eval2: k2 = f(ymid); ynew = p + 0.05*k2 (fp32 + packed)
    float* yOut = (s == 9) ? (float*)d_out : yF;
    fused_feval<<<grid, blkd, 0, stream>>>(ympk, w1p, w2p, b1, b2, pF, yOut, ypk, 2);
  }
}

// Round 9
// 1584.805 us; speedup vs baseline: 1.1222x; 1.1222x over previous
//
#include <hip/hip_runtime.h>
#include <hip/hip_bf16.h>
#include <cstdint>

// Neural ODE: 10 Heun steps of f(y) = tanh(y@W1 + b1)@W2 + b2
// BATCH=8192, D=512, H=2048, dt=0.1
// R9 (= R8 design, compile-clean): merged pipeline (phase1(c) + phase2(c-1)
// in ONE barrier region; R7 proved splitting exposes weight-load latency)
// + CW=512 so both phases run 2 tiles/wave sharing A-frag ds_reads.
// 96 KB dynamic LDS (yA 32K + 2x32K hA double buffer), computed-offset
// pointers (pointer ARRAY init from dynamic LDS miscompiles). Barriers per
// f-eval 10->6, ds_read_b128/wave 384->256, stateIn prefetched to regs.

#define BATCHN 8192
#define DDIM 512
#define HDIM 2048
#define CW 512          // chunk width over H
#define NCH (HDIM / CW) // 4

typedef short short8 __attribute__((ext_vector_type(8)));
typedef float floatx4 __attribute__((ext_vector_type(4)));

__device__ __forceinline__ unsigned short f2bf(float f) {
  union { __hip_bfloat16 h; unsigned short u; } cv;
  cv.h = __float2bfloat16(f);
  return cv.u;
}

__device__ __forceinline__ float fast_tanh(float x) {
  float e = __expf(2.0f * x);
  return 1.0f - 2.0f / (e + 1.0f);
}

__device__ __forceinline__ void glds16(const void* g, void* l) {
  __builtin_amdgcn_global_load_lds(
      (const __attribute__((address_space(1))) void*)(uintptr_t)g,
      (__attribute__((address_space(3))) void*)(uint32_t)(uintptr_t)l,
      16, 0, 0);
}

// Fragment conventions (verified R1-R7):
//  A-frag (16x16x32): lane holds A[m = l15][k = quad*8 + j], j=0..7 (16B)
//  B-frag:            lane holds B[n = l15][k = quad*8 + j]
//  C/D:               row = quad*4 + r, col = l15
// Packed buffers: frag f at [(f*64 + lane)*8] halves.
//  yPack: f = rb*16 + ks   (rb = batch-row/16, ks = D k-step 0..15)
//  w1p:   f = nb*16 + kb   (nb = H col-tile 0..127, kb = D k-step 0..15)
//  w2p:   f = nb*64 + kb   (nb = D col-tile 0..31,  kb = H k-step 0..63)

__global__ __launch_bounds__(1024, 4) void fused_feval(
    const unsigned short* __restrict__ yPack,   // packed bf16 eval input
    const unsigned short* __restrict__ w1p,
    const unsigned short* __restrict__ w2p,
    const float* __restrict__ b1,
    const float* __restrict__ b2,
    const float* __restrict__ stateIn,   // EPI1: y fp32 ; EPI2: p fp32
    float* __restrict__ stateOut,        // EPI1: p      ; EPI2: ynew
    unsigned short* __restrict__ outPack,// packed bf16 next-eval input
    int epi) {                           // 1 or 2
  extern __shared__ unsigned short smem[];
  unsigned short* yA    = smem;          // 32 KB, frags (mt*16+ks)
  unsigned short* hBase = smem + 16384;  // 2 x 32 KB double buffer

  const int tid  = threadIdx.x;
  const int lane = tid & 63;
  const int w    = tid >> 6;    // wave 0..15
  const int quad = lane >> 4;
  const int l15  = lane & 15;
  const int blk  = blockIdx.x;  // 0..255
  const int B0   = blk * 32;    // slab base row

  // phase0: linear copy of this block's 32 KB packed y-slab into LDS.
  {
    const unsigned short* src = yPack + (size_t)blk * (32 * 512);
    glds16(src + (size_t)tid * 8, &yA[tid * 8]);
    glds16(src + (size_t)(1024 + tid) * 8, &yA[(1024 + tid) * 8]);
  }

  // Prefetch epilogue state (16 floats/thread) while LDS fill is in flight.
  float sf[2][2][4];
#pragma unroll
  for (int i = 0; i < 2; ++i) {
    const int ncol = (w * 2 + i) * 16 + l15;
#pragma unroll
    for (int mt = 0; mt < 2; ++mt)
#pragma unroll
      for (int r = 0; r < 4; ++r) {
        const int row = B0 + mt * 16 + quad * 4 + r;
        sf[i][mt][r] = stateIn[(size_t)row * DDIM + ncol];
      }
  }
  __syncthreads();

  floatx4 accY[2][2] = {};  // ymid acc: (mt, i), cols (w*2+i)*16 + l15

  for (int c = 0; c < NCH; ++c) {
    // ---- phase1: h chunk c = tanh(y @ W1-slice + b1), 2 nb1 tiles/wave ----
    floatx4 acc1[2][2] = {};  // (t, mt)
#pragma unroll
    for (int ks = 0; ks < 16; ++ks) {
      short8 a0 = *(const short8*)&yA[((0 * 16 + ks) * 64 + lane) * 8];
      short8 a1 = *(const short8*)&yA[((1 * 16 + ks) * 64 + lane) * 8];
#pragma unroll
      for (int t = 0; t < 2; ++t) {
        const int nb1 = c * 32 + w * 2 + t;  // H col-tile 0..127
        short8 b = *(const short8*)&w1p[((size_t)(nb1 * 16 + ks) * 64 + lane) * 8];
        acc1[t][0] = __builtin_amdgcn_mfma_f32_16x16x32_bf16(a0, b, acc1[t][0], 0, 0, 0);
        acc1[t][1] = __builtin_amdgcn_mfma_f32_16x16x32_bf16(a1, b, acc1[t][1], 0, 0, 0);
      }
    }
    // bias + tanh + scatter into hBase[(c&1)] in A-frag layout
    {
      unsigned short* hbuf = hBase + (c & 1) * 16384;
#pragma unroll
      for (int t = 0; t < 2; ++t) {
        const int kloc = (w * 2 + t) * 16 + l15;   // 0..511
        const float bb = b1[c * CW + kloc];
        const int ksa = kloc >> 5;
        const int qa  = (kloc & 31) >> 3;
        const int kb7 = kloc & 7;
#pragma unroll
        for (int mt = 0; mt < 2; ++mt)
#pragma unroll
          for (int r = 0; r < 4; ++r) {
            const int m15 = quad * 4 + r;          // C row -> A-frag m
            hbuf[((mt * 16 + ksa) * 64 + qa * 16 + m15) * 8 + kb7] =
                f2bf(fast_tanh(acc1[t][mt][r] + bb));
          }
      }
    }
    // ---- phase2 (same region): accY += h chunk c-1 @ W2-slice ----
    if (c > 0) {
      const unsigned short* hprev = hBase + ((c - 1) & 1) * 16384;
#pragma unroll
      for (int kb = 0; kb < 16; ++kb) {
        short8 a0 = *(const short8*)&hprev[((0 * 16 + kb) * 64 + lane) * 8];
        short8 a1 = *(const short8*)&hprev[((1 * 16 + kb) * 64 + lane) * 8];
        const int kbg = (c - 1) * 16 + kb;         // global H k-step 0..63
#pragma unroll
        for (int i = 0; i < 2; ++i) {
          const int nb2 = w * 2 + i;               // D col-tile 0..31
          short8 b = *(const short8*)&w2p[((size_t)(nb2 * 64 + kbg) * 64 + lane) * 8];
          accY[0][i] = __builtin_amdgcn_mfma_f32_16x16x32_bf16(a0, b, accY[0][i], 0, 0, 0);
          accY[1][i] = __builtin_amdgcn_mfma_f32_16x16x32_bf16(a1, b, accY[1][i], 0, 0, 0);
        }
      }
    }
    __syncthreads();
  }
  // tail phase2: chunk NCH-1 (synced by last region barrier)
  {
    const unsigned short* hprev = hBase + ((NCH - 1) & 1) * 16384;
#pragma unroll
    for (int kb = 0; kb < 16; ++kb) {
      short8 a0 = *(const short8*)&hprev[((0 * 16 + kb) * 64 + lane) * 8];
      short8 a1 = *(const short8*)&hprev[((1 * 16 + kb) * 64 + lane) * 8];
      const int kbg = (NCH - 1) * 16 + kb;
#pragma unroll
      for (int i = 0; i < 2; ++i) {
        const int nb2 = w * 2 + i;
        short8 b = *(const short8*)&w2p[((size_t)(nb2 * 64 + kbg) * 64 + lane) * 8];
        accY[0][i] = __builtin_amdgcn_mfma_f32_16x16x32_bf16(a0, b, accY[0][i], 0, 0, 0);
        accY[1][i] = __builtin_amdgcn_mfma_f32_16x16x32_bf16(a1, b, accY[1][i], 0, 0, 0);
      }
    }
  }
  __syncthreads();  // ensure all waves done reading hBase[0] (tail reads buf 1)

  // Epilogue: add b2, Heun combine (state prefetched in sf), pack bf16 result.
  {
    unsigned short* pbuf = hBase;  // reuse buffer 0 as 32 KB pack staging
#pragma unroll
    for (int i = 0; i < 2; ++i) {
      const int ncol = (w * 2 + i) * 16 + l15;   // 0..511
      const float bb = b2[ncol];
      const int ksa = ncol >> 5;
      const int qa  = (ncol & 31) >> 3;
      const int nb7 = ncol & 7;
#pragma unroll
      for (int mt = 0; mt < 2; ++mt)
#pragma unroll
        for (int r = 0; r < 4; ++r) {
          const int row = B0 + mt * 16 + quad * 4 + r;
          const size_t idx = (size_t)row * DDIM + ncol;
          const float v = accY[mt][i][r] + bb;
          float nv;
          if (epi == 1) {
            const float y = sf[i][mt][r];
            stateOut[idx] = y + 0.05f * v;   // p = y + (dt/2)*k1
            nv = y + 0.1f * v;               // ymid
          } else {
            const float yn = sf[i][mt][r] + 0.05f * v;  // ynew = p + (dt/2)*k2
            stateOut[idx] = yn;
            nv = yn;
          }
          const int m15 = quad * 4 + r;
          pbuf[((mt * 16 + ksa) * 64 + qa * 16 + m15) * 8 + nb7] = f2bf(nv);
        }
    }
    __syncthreads();
    unsigned short* dst = outPack + (size_t)blk * (32 * 512);
#pragma unroll
    for (int p = 0; p < 2; ++p) {
      short8 v = *(const short8*)&pbuf[(size_t)(p * 1024 + tid) * 8];
      *(short8*)&dst[(size_t)(p * 1024 + tid) * 8] = v;
    }
  }
}

// Pack weight [K][N] fp32 -> B-frag order: frag f = nb*KB + kb,
// lane entry = src[kb*32 + quad*8 + j][nb*16 + l15].
__global__ void pack_b(const float* __restrict__ src, unsigned short* __restrict__ dst,
                       int KB, int N) {
  const int t = blockIdx.x * 256 + threadIdx.x;
  const int lane = t & 63, f = t >> 6;
  const int nb = f / KB, kb = f % KB;
  const int quad = lane >> 4, l15 = lane & 15;
  const int k0 = kb * 32 + quad * 8, n = nb * 16 + l15;
  short8 v;
#pragma unroll
  for (int j = 0; j < 8; ++j)
    v[j] = (short)f2bf(src[(size_t)(k0 + j) * N + n]);
  *(short8*)&dst[(size_t)t * 8] = v;
}

// y0 fp32 [8192][512] -> yF fp32 copy + packed bf16 A-frags.
__global__ void pack_y(const float* __restrict__ y0, float* __restrict__ yF,
                       unsigned short* __restrict__ ypk) {
  const int t = blockIdx.x * 256 + threadIdx.x;
  const int lane = t & 63, f = t >> 6;
  const int rb = f >> 4, ks = f & 15;
  const int quad = lane >> 4, l15 = lane & 15;
  const int row = rb * 16 + l15, c0 = ks * 32 + quad * 8;
  short8 v;
#pragma unroll
  for (int j = 0; j < 8; ++j) {
    const float x = y0[(size_t)row * DDIM + c0 + j];
    yF[(size_t)row * DDIM + c0 + j] = x;
    v[j] = (short)f2bf(x);
  }
  *(short8*)&ypk[(size_t)t * 8] = v;
}

extern "C" void kernel_launch(void* const* d_in, const int* in_sizes, int n_in,
                              void* d_out, int out_size, void* d_ws, size_t ws_size,
                              hipStream_t stream) {
  const float* y0 = (const float*)d_in[0];
  const float* W1 = (const float*)d_in[1];  // [512][2048]
  const float* b1 = (const float*)d_in[2];  // [2048]
  const float* W2 = (const float*)d_in[3];  // [2048][512]
  const float* b2 = (const float*)d_in[4];  // [512]

  char* ws = (char*)d_ws;
  float*          yF   = (float*)(ws);                         // 16 MB
  float*          pF   = (float*)(ws + (size_t)(16u << 20));   // 16 MB
  unsigned short* ypk  = (unsigned short*)(ws + (size_t)(32u << 20)); // 8 MB
  unsigned short* ympk = (unsigned short*)(ws + (size_t)(40u << 20)); // 8 MB
  unsigned short* w1p  = (unsigned short*)(ws + (size_t)(48u << 20)); // 2 MB
  unsigned short* w2p  = (unsigned short*)(ws + (size_t)(50u << 20)); // 2 MB

  // Allow 96 KB dynamic LDS (host-side attribute; idempotent, capture-safe).
  (void)hipFuncSetAttribute((const void*)fused_feval,
                            hipFuncAttributeMaxDynamicSharedMemorySize, 98304);

  // Pre-pass: pack weights (2048 frags each) and y0 (8192 frags).
  pack_b<<<512, 256, 0, stream>>>(W1, w1p, 16, HDIM);
  pack_b<<<512, 256, 0, stream>>>(W2, w2p, 64, DDIM);
  pack_y<<<2048, 256, 0, stream>>>(y0, yF, ypk);

  const dim3 grid(256), blkd(1024);
  const size_t shmem = 98304;
  for (int s = 0; s < 10; ++s) {
    // eval1: k1 = f(y); p = y + 0.05*k1; ymid = y + 0.1*k1 (packed)
    fused_feval<<<grid, blkd, shmem, stream>>>(ypk, w1p, w2p, b1, b2, yF, pF, ympk, 1);
    // eval2: k2 = f(ymid); ynew = p + 0.05*k2 (fp32 + packed)
    float* yOut = (s == 9) ? (float*)d_out : yF;
    fused_feval<<<grid, blkd, shmem, stream>>>(ympk, w1p, w2p, b1, b2, pF, yOut, ypk, 2);
  }
}

// Round 10
// 1275.383 us; speedup vs baseline: 1.3945x; 1.2426x over previous
//
#include <hip/hip_runtime.h>
#include <hip/hip_bf16.h>
#include <cstdint>

// Neural ODE: 10 Heun steps of f(y) = tanh(y@W1 + b1)@W2 + b2
// BATCH=8192, D=512, H=2048, dt=0.1
// R10: switch to mfma_f32_32x32x16_bf16 -- 2x FLOP per fragment byte, so
// MFMA instr count, LDS A-reads, and B-load count all halve at constant
// weight bytes. Slab=32 rows (1 m-tile), CW=512: phase1 = 1 H-tile(32)/wave,
// phase2 = 1 D-tile(32)/wave -> ONE contiguous 32KB weight stream per wave
// per phase (R6's proven pattern; R7/R9's dual streams regressed). Merged
// barrier region, double-buffered hA, 96 KB dynamic LDS, 6 barriers/f-eval.

#define BATCHN 8192
#define DDIM 512
#define HDIM 2048
#define CW 512          // chunk width over H
#define NCH (HDIM / CW) // 4

typedef short short8 __attribute__((ext_vector_type(8)));
typedef float floatx16 __attribute__((ext_vector_type(16)));

__device__ __forceinline__ unsigned short f2bf(float f) {
  union { __hip_bfloat16 h; unsigned short u; } cv;
  cv.h = __float2bfloat16(f);
  return cv.u;
}

__device__ __forceinline__ float fast_tanh(float x) {
  float e = __expf(2.0f * x);
  return 1.0f - 2.0f / (e + 1.0f);
}

__device__ __forceinline__ void glds16(const void* g, void* l) {
  __builtin_amdgcn_global_load_lds(
      (const __attribute__((address_space(1))) void*)(uintptr_t)g,
      (__attribute__((address_space(3))) void*)(uint32_t)(uintptr_t)l,
      16, 0, 0);
}

// 32x32x16 fragment conventions:
//  A-frag: lane holds A[m = lane&31][k = (lane>>5)*8 + j], j=0..7 (16B)
//  B-frag: lane holds B[n = lane&31][k = (lane>>5)*8 + j]   (BT row-major)
//  C/D:    col = lane&31, row = (reg&3) + 8*(reg>>2) + 4*(lane>>5)  [m74/m101]
// Packed buffers: frag f at [(f*64 + lane)*8] halves.
//  yPack: f = blk*32 + ks  (blk = batch-row/32, ks = D k-step 0..31)
//  w1p:   f = nb*32 + ks   (nb = H col-tile/32: 0..63,  ks = D k-step 0..31)
//  w2p:   f = nb*128 + kb  (nb = D col-tile/32: 0..15,  kb = H k-step 0..127)

__global__ __launch_bounds__(1024, 4) void fused_feval(
    const unsigned short* __restrict__ yPack,   // packed bf16 eval input
    const unsigned short* __restrict__ w1p,
    const unsigned short* __restrict__ w2p,
    const float* __restrict__ b1,
    const float* __restrict__ b2,
    const float* __restrict__ stateIn,   // EPI1: y fp32 ; EPI2: p fp32
    float* __restrict__ stateOut,        // EPI1: p      ; EPI2: ynew
    unsigned short* __restrict__ outPack,// packed bf16 next-eval input
    int epi) {                           // 1 or 2
  extern __shared__ unsigned short smem[];
  unsigned short* yA    = smem;          // 32 KB: 32 A-frags (ks 0..31)
  unsigned short* hBase = smem + 16384;  // 2 x 32 KB hA double buffer

  const int tid  = threadIdx.x;
  const int lane = tid & 63;
  const int w    = tid >> 6;    // wave 0..15
  const int l31  = lane & 31;
  const int hup  = lane >> 5;   // k-block half (0/1)
  const int blk  = blockIdx.x;  // 0..255
  const int B0   = blk * 32;    // slab base row

  // phase0: linear copy of this block's 32 KB packed y-slab into LDS.
  {
    const unsigned short* src = yPack + (size_t)blk * (32 * 512);
    glds16(src + (size_t)tid * 8, &yA[tid * 8]);
    glds16(src + (size_t)(1024 + tid) * 8, &yA[(1024 + tid) * 8]);
  }
  __syncthreads();

  floatx16 accY = {};  // ymid tile: D cols w*32 + l31

  // scatter/pack helper indices (lane-fixed)
  const int fb  = (l31 >> 4);       // frag sub-index within wave pair
  const int hi  = (l31 & 8) >> 3;   // k-block half of target frag
  const int j7  = l31 & 7;

  for (int c = 0; c < NCH; ++c) {
    // ---- phase1: h tile (c*16+w) = tanh(y @ W1-slice + b1) ----
    floatx16 acc1 = {};
    {
      const unsigned short* w1base = w1p + ((size_t)(c * 16 + w) * 32) * 64 * 8;
#pragma unroll
      for (int ks = 0; ks < 32; ++ks) {
        short8 a = *(const short8*)&yA[(ks * 64 + lane) * 8];
        short8 b = *(const short8*)&w1base[((size_t)ks * 64 + lane) * 8];
        acc1 = __builtin_amdgcn_mfma_f32_32x32x16_bf16(a, b, acc1, 0, 0, 0);
      }
    }
    // bias + tanh + scatter into hBase[c&1] as A-frags (k = chunk-local h-col)
    {
      unsigned short* hbuf = hBase + (c & 1) * 16384;
      const float bb = b1[c * CW + w * 32 + l31];
      const int fbase = w * 2 + fb;            // frag 0..31 within chunk
#pragma unroll
      for (int e = 0; e < 16; ++e) {
        const int row = (e & 3) + 8 * (e >> 2) + 4 * hup;  // batch row 0..31
        hbuf[(fbase * 64 + row + 32 * hi) * 8 + j7] =
            f2bf(fast_tanh(acc1[e] + bb));
      }
    }
    // ---- phase2 (same region): accY += h chunk c-1 @ W2-slice ----
    if (c > 0) {
      const unsigned short* hprev = hBase + ((c - 1) & 1) * 16384;
      const unsigned short* w2base =
          w2p + ((size_t)(w * 128 + (c - 1) * 32)) * 64 * 8;
#pragma unroll
      for (int kb = 0; kb < 32; ++kb) {
        short8 a = *(const short8*)&hprev[(kb * 64 + lane) * 8];
        short8 b = *(const short8*)&w2base[((size_t)kb * 64 + lane) * 8];
        accY = __builtin_amdgcn_mfma_f32_32x32x16_bf16(a, b, accY, 0, 0, 0);
      }
    }
    __syncthreads();
  }
  // tail phase2: chunk NCH-1 (buffer 1; synced by last region barrier)
  {
    const unsigned short* hprev = hBase + ((NCH - 1) & 1) * 16384;
    const unsigned short* w2base =
        w2p + ((size_t)(w * 128 + (NCH - 1) * 32)) * 64 * 8;
#pragma unroll
    for (int kb = 0; kb < 32; ++kb) {
      short8 a = *(const short8*)&hprev[(kb * 64 + lane) * 8];
      short8 b = *(const short8*)&w2base[((size_t)kb * 64 + lane) * 8];
      accY = __builtin_amdgcn_mfma_f32_32x32x16_bf16(a, b, accY, 0, 0, 0);
    }
  }

  // Epilogue: add b2, Heun combine with fp32 state, pack bf16 result.
  // pbuf = buffer 0: last read in region c=3 (phase2 of c=2), barrier after.
  {
    unsigned short* pbuf = hBase;
    const int ncol = w * 32 + l31;             // D column 0..511
    const float bb = b2[ncol];
    const int fy = w * 2 + fb;                 // yPack frag 0..31
#pragma unroll
    for (int e = 0; e < 16; ++e) {
      const int row = (e & 3) + 8 * (e >> 2) + 4 * hup;  // batch row 0..31
      const size_t idx = (size_t)(B0 + row) * DDIM + ncol;
      const float v = accY[e] + bb;
      float nv;
      if (epi == 1) {
        const float y = stateIn[idx];
        stateOut[idx] = y + 0.05f * v;   // p = y + (dt/2)*k1
        nv = y + 0.1f * v;               // ymid
      } else {
        const float yn = stateIn[idx] + 0.05f * v;  // ynew = p + (dt/2)*k2
        stateOut[idx] = yn;
        nv = yn;
      }
      pbuf[(fy * 64 + row + 32 * hi) * 8 + j7] = f2bf(nv);
    }
    __syncthreads();
    unsigned short* dst = outPack + (size_t)blk * (32 * 512);
#pragma unroll
    for (int p = 0; p < 2; ++p) {
      short8 v = *(const short8*)&pbuf[(size_t)(p * 1024 + tid) * 8];
      *(short8*)&dst[(size_t)(p * 1024 + tid) * 8] = v;
    }
  }
}

// Pack weight [K][N] fp32 -> 32-wide B-frag order: frag f = nb*KB + kb,
// lane entry = src[kb*16 + (lane>>5)*8 + j][nb*32 + (lane&31)].
__global__ void pack_b(const float* __restrict__ src, unsigned short* __restrict__ dst,
                       int KB, int N) {
  const int t = blockIdx.x * 256 + threadIdx.x;
  const int lane = t & 63, f = t >> 6;
  const int nb = f / KB, kb = f % KB;
  const int k0 = kb * 16 + (lane >> 5) * 8, n = nb * 32 + (lane & 31);
  short8 v;
#pragma unroll
  for (int j = 0; j < 8; ++j)
    v[j] = (short)f2bf(src[(size_t)(k0 + j) * N + n]);
  *(short8*)&dst[(size_t)t * 8] = v;
}

// y0 fp32 [8192][512] -> yF fp32 copy + packed bf16 32-wide A-frags.
__global__ void pack_y(const float* __restrict__ y0, float* __restrict__ yF,
                       unsigned short* __restrict__ ypk) {
  const int t = blockIdx.x * 256 + threadIdx.x;
  const int lane = t & 63, f = t >> 6;
  const int bk = f >> 5, ks = f & 31;
  const int row = bk * 32 + (lane & 31), c0 = ks * 16 + (lane >> 5) * 8;
  short8 v;
#pragma unroll
  for (int j = 0; j < 8; ++j) {
    const float x = y0[(size_t)row * DDIM + c0 + j];
    yF[(size_t)row * DDIM + c0 + j] = x;
    v[j] = (short)f2bf(x);
  }
  *(short8*)&ypk[(size_t)t * 8] = v;
}

extern "C" void kernel_launch(void* const* d_in, const int* in_sizes, int n_in,
                              void* d_out, int out_size, void* d_ws, size_t ws_size,
                              hipStream_t stream) {
  const float* y0 = (const float*)d_in[0];
  const float* W1 = (const float*)d_in[1];  // [512][2048]
  const float* b1 = (const float*)d_in[2];  // [2048]
  const float* W2 = (const float*)d_in[3];  // [2048][512]
  const float* b2 = (const float*)d_in[4];  // [512]

  char* ws = (char*)d_ws;
  float*          yF   = (float*)(ws);                         // 16 MB
  float*          pF   = (float*)(ws + (size_t)(16u << 20));   // 16 MB
  unsigned short* ypk  = (unsigned short*)(ws + (size_t)(32u << 20)); // 8 MB
  unsigned short* ympk = (unsigned short*)(ws + (size_t)(40u << 20)); // 8 MB
  unsigned short* w1p  = (unsigned short*)(ws + (size_t)(48u << 20)); // 2 MB
  unsigned short* w2p  = (unsigned short*)(ws + (size_t)(50u << 20)); // 2 MB

  // Allow 96 KB dynamic LDS (host-side attribute; idempotent, capture-safe).
  (void)hipFuncSetAttribute((const void*)fused_feval,
                            hipFuncAttributeMaxDynamicSharedMemorySize, 98304);

  // Pre-pass: pack weights (2048 frags each: W1 64x32, W2 16x128) and y0.
  pack_b<<<512, 256, 0, stream>>>(W1, w1p, 32, HDIM);
  pack_b<<<512, 256, 0, stream>>>(W2, w2p, 128, DDIM);
  pack_y<<<2048, 256, 0, stream>>>(y0, yF, ypk);

  const dim3 grid(256), blkd(1024);
  const size_t shmem = 98304;
  for (int s = 0; s < 10; ++s) {
    // eval1: k1 = f(y); p = y + 0.05*k1; ymid = y + 0.1*k1 (packed)
    fused_feval<<<grid, blkd, shmem, stream>>>(ypk, w1p, w2p, b1, b2, yF, pF, ympk, 1);
    // eval2: k2 = f(ymid); ynew = p + 0.05*k2 (fp32 + packed)
    float* yOut = (s == 9) ? (float*)d_out : yF;
    fused_feval<<<grid, blkd, shmem, stream>>>(ympk, w1p, w2p, b1, b2, pF, yOut, ypk, 2);
  }
}